// Round 10
// baseline (293.811 us; speedup 1.0000x reference)
//
#include <hip/hip_runtime.h>
#include <hip/hip_bf16.h>
#include <cstdint>
#include <cstddef>

#define NTOKS  2048
#define DMODEL 1024
#define DFFN   4096
#define NEXP   8
#define TS256  24   // max live 256-row M-tiles
#define TS128  40   // max live 128-row M-tiles

typedef __attribute__((ext_vector_type(8))) short short8;
typedef __attribute__((ext_vector_type(4))) float f32x4;
typedef __attribute__((ext_vector_type(4))) unsigned short u16x4;
typedef __attribute__((ext_vector_type(8))) unsigned short u16x8;

// ---------------- workspace layout ----------------
static constexpr size_t alignup(size_t x) { return (x + 255) & ~(size_t)255; }
static constexpr size_t OFF_XB   = 0;                                            // (NTOKS+1) x DMODEL bf16
static constexpr size_t OFF_CNT  = alignup(OFF_XB + (size_t)(NTOKS + 1) * DMODEL * 2);
static constexpr size_t OFF_OFFS = OFF_CNT + 256;
static constexpr size_t OFF_TOKE = OFF_OFFS + 256;
static constexpr size_t OFF_TOKT = OFF_TOKE + (size_t)NTOKS * 2 * 4;
static constexpr size_t OFF_TOKS = OFF_TOKT + (size_t)NTOKS * 2 * 4;
static constexpr size_t OFF_TI   = alignup(OFF_TOKS + (size_t)NTOKS * 2 * 4);    // TS256 int2
static constexpr size_t OFF_TI2  = OFF_TI + 256;                                 // TS128 int2
static constexpr size_t OFF_CAP  = alignup(OFF_TI2 + TS128 * 8);                 // NEXP*NTOKS int
static constexpr size_t OFF_H    = alignup(OFF_CAP + (size_t)NEXP * NTOKS * 4);  // (4096+256) x DFFN bf16
static constexpr size_t OFF_Y    = alignup(OFF_H + (size_t)(NTOKS * 2 + 256) * DFFN * 2); // 2 slabs f32
static constexpr size_t OFF_WB   = alignup(OFF_Y + (size_t)2 * NTOKS * 2 * DMODEL * 4);  // E*D*DFF bf16

__device__ inline unsigned short f2bf(float f) {
  __hip_bfloat16 h = __float2bfloat16(f);
  return __builtin_bit_cast(unsigned short, h);
}

__device__ inline void gload16(const void* g, void* l) {
  __builtin_amdgcn_global_load_lds((const __attribute__((address_space(1))) unsigned int*)g,
                                   (__attribute__((address_space(3))) unsigned int*)l, 16, 0, 0);
}

// ---------------- kernel 1: x f32 -> bf16 (+zero row), zero counts ----------------
__global__ __launch_bounds__(256) void k_convert(const float* __restrict__ x,
                                                 unsigned short* __restrict__ xb,
                                                 int* __restrict__ cnt) {
  if (blockIdx.x == 0 && threadIdx.x < NEXP) cnt[threadIdx.x] = 0;
  size_t base = ((size_t)blockIdx.x * 256 + threadIdx.x) * 8;
  const size_t total = (size_t)(NTOKS + 1) * DMODEL;
  if (base >= total) return;
  u16x8 o;
  if (base < (size_t)NTOKS * DMODEL) {
    f32x4 a = *(const f32x4*)(x + base);
    f32x4 b = *(const f32x4*)(x + base + 4);
#pragma unroll
    for (int j = 0; j < 4; ++j) { o[j] = f2bf(a[j]); o[4 + j] = f2bf(b[j]); }
  } else {
#pragma unroll
    for (int j = 0; j < 8; ++j) o[j] = 0;
  }
  *(u16x8*)(xb + base) = o;
}

// ---------------- weight transpose+convert: W[e][R][C] f32 -> WT[e][C][R] bf16 ----------------
template <int R, int C>
__global__ __launch_bounds__(256) void k_transconv(const float* __restrict__ W,
                                                   unsigned short* __restrict__ WT) {
  __shared__ unsigned short T[64][66];
  const int e = blockIdx.z;
  const int c0 = blockIdx.x * 64, r0 = blockIdx.y * 64;
  const float* Wp = W + (size_t)e * R * C;
  unsigned short* Tp = WT + (size_t)e * R * C;
  const int tid = threadIdx.x;
  const int rr = tid >> 4, cc = (tid & 15) << 2;
#pragma unroll
  for (int i = 0; i < 4; ++i) {
    int r = rr + (i << 4);
    f32x4 v = *(const f32x4*)(Wp + (size_t)(r0 + r) * C + c0 + cc);
    T[r][cc]     = f2bf(v[0]);
    T[r][cc + 1] = f2bf(v[1]);
    T[r][cc + 2] = f2bf(v[2]);
    T[r][cc + 3] = f2bf(v[3]);
  }
  __syncthreads();
  const int c = tid >> 2, kc = (tid & 3) << 4;
  u16x8 o0, o1;
#pragma unroll
  for (int i = 0; i < 8; ++i) { o0[i] = T[kc + i][c]; o1[i] = T[kc + 8 + i][c]; }
  unsigned short* dst = Tp + (size_t)(c0 + c) * R + r0 + kc;
  *(u16x8*)(dst) = o0;
  *(u16x8*)(dst + 8) = o1;
}

// ---------------- kernel 2: gate (one wave per token) ----------------
__global__ __launch_bounds__(256) void k_gate(const float* __restrict__ x,
                                              const float* __restrict__ Wg,
                                              const float* __restrict__ bg,
                                              int* __restrict__ cnt,
                                              int* __restrict__ tok_e,
                                              int* __restrict__ tok_t,
                                              float* __restrict__ tok_s,
                                              int* __restrict__ cap) {
  const int w = threadIdx.x >> 6, lane = threadIdx.x & 63;
  const int n = blockIdx.x * 4 + w;
  float acc[8];
#pragma unroll
  for (int e = 0; e < 8; ++e) acc[e] = 0.f;
  const float* xr = x + (size_t)n * DMODEL;
#pragma unroll 4
  for (int it = 0; it < DMODEL / 64; ++it) {
    int d = it * 64 + lane;
    float xv = xr[d];
    f32x4 w0 = *(const f32x4*)(Wg + d * 8);
    f32x4 w1 = *(const f32x4*)(Wg + d * 8 + 4);
#pragma unroll
    for (int j = 0; j < 4; ++j) { acc[j] += xv * w0[j]; acc[4 + j] += xv * w1[j]; }
  }
#pragma unroll
  for (int e = 0; e < 8; ++e)
#pragma unroll
    for (int off = 32; off; off >>= 1) acc[e] += __shfl_xor(acc[e], off, 64);
  if (lane == 0) {
    float l[8];
#pragma unroll
    for (int e = 0; e < 8; ++e) l[e] = acc[e] + bg[e];
    int i0 = 0; float v0 = l[0];
#pragma unroll
    for (int e = 1; e < 8; ++e) if (l[e] > v0) { v0 = l[e]; i0 = e; }
    int i1 = (i0 == 0) ? 1 : 0; float v1 = l[i1];
#pragma unroll
    for (int e = 0; e < 8; ++e) if (e != i0 && l[e] > v1) { v1 = l[e]; i1 = e; }
    float t = expf(v1 - v0);
    float inv = 1.f / (1.f + t);
    float s0 = inv, s1 = t * inv;
    int t0 = atomicAdd(&cnt[i0], 1);
    int t1 = atomicAdd(&cnt[i1], 1);
    cap[i0 * NTOKS + t0] = n;
    cap[i1 * NTOKS + t1] = n;
    tok_e[2 * n] = i0; tok_e[2 * n + 1] = i1;
    tok_t[2 * n] = t0; tok_t[2 * n + 1] = t1;
    tok_s[2 * n] = s0; tok_s[2 * n + 1] = s1;
  }
}

// ---------------- kernel 3: offsets + dense live-tile tables (256- and 128-row) ----------------
__global__ void k_scan(const int* __restrict__ cnt, int* __restrict__ offs,
                       int2* __restrict__ ti256, int2* __restrict__ ti128) {
  if (threadIdx.x == 0) {
    int s = 0;
#pragma unroll
    for (int e = 0; e < NEXP; ++e) { offs[e] = s; s += cnt[e]; }
    int a = 0;
    for (int e = 0; e < NEXP; ++e)
      for (int t = 0; t * 256 < cnt[e]; ++t) { ti256[a] = make_int2(e, t * 256); ++a; }
    for (; a < TS256; ++a) ti256[a] = make_int2(-1, 0);
    int b = 0;
    for (int e = 0; e < NEXP; ++e)
      for (int t = 0; t * 128 < cnt[e]; ++t) { ti128[b] = make_int2(e, t * 128); ++b; }
    for (; b < TS128; ++b) ti128[b] = make_int2(-1, 0);
  }
}

// ---------------- GEMM1: 256x256xBK64, counted-vmcnt half-tile pipeline ----------------
// Stripe-interleaved wave ownership: wave (wr,wc) output rows {mh*128+wr*64..}, cols
// {nh*128+wc*32..} per quadrant (mh,nh) -> phase (mh,nh) collectively reads exactly
// A-half mh and B-half nh. Per tile t, 4 phases in order (0,0)(0,1)(1,0)(1,1); phase p
// stages ONE half-tile of t+1 into buf^1 (order A0,B0,B1,A1 = first-consumption order),
// then s_waitcnt vmcnt(6) (counted: the 3 not-yet-needed halves = 6 loads may fly; never
// drains), one s_barrier, ds_read frags, setprio(1) 16 MFMA setprio(0). Uniform loop via
// wrap-around dummy stage at the tail (written, never read) keeps vmcnt arithmetic exact.
// Race-freedom: every stage targets buf^1 while tile t reads buf; lagging waves (at most
// one phase behind) read A1/B1 of buf^1 only at (t-1,ph4) while ph1 stages A0 - disjoint.
__global__ __launch_bounds__(512, 2) void k_gemm8(const unsigned short* __restrict__ Asrc,
                                                  const unsigned short* __restrict__ Bsrc,
                                                  const float* __restrict__ bias,
                                                  const int* __restrict__ cnt,
                                                  const int* __restrict__ offs,
                                                  const int2* __restrict__ tinfo,
                                                  const int* __restrict__ cap,
                                                  unsigned short* __restrict__ hout) {
  constexpr int KTOT = DMODEL, NTOT = DFFN;
  constexpr int NT = KTOT / 64;         // 16 K-tiles
  const int2 ti = tinfo[blockIdx.y];
  if (ti.x < 0) return;
  const int e = ti.x, t0 = ti.y;
  const int c = cnt[e];
  const int base = offs[e] + t0;
  const int n0 = blockIdx.x * 256;

  const int tid = threadIdx.x, w = tid >> 6, lane = tid & 63;
  const int l15 = lane & 15, lq = lane >> 4;
  const int wr = w >> 2, wc = w & 3;    // 2M x 4N wave grid

  __shared__ unsigned short As[2][256 * 64];
  __shared__ unsigned short Bs[2][256 * 64];

  const int rl = tid >> 3;
  const int sw = ((tid & 7) ^ (rl & 7)) << 3;    // pre-swizzled source chunk (shorts)
  const unsigned short* aptr[4];                 // row-groups of 64 rows
#pragma unroll
  for (int r = 0; r < 4; ++r) {
    int row = r * 64 + rl;
    size_t gr = (size_t)((t0 + row < c) ? cap[e * NTOKS + t0 + row] : NTOKS);
    aptr[r] = Asrc + gr * (size_t)KTOT + sw;
  }
  const unsigned short* Be = Bsrc + (size_t)e * ((size_t)KTOT * NTOT);
  const unsigned short* bptr[4];
#pragma unroll
  for (int r = 0; r < 4; ++r)
    bptr[r] = Be + (size_t)(n0 + r * 64 + rl) * KTOT + sw;

  // stage one half-tile (2 gload16/thread). h = half index (0/1); tile tl (wrapped).
  auto stageAh = [&](int tl, int h) {
    const int b = tl & 1;
    const int k0 = (tl % NT) << 6;
#pragma unroll
    for (int r = 0; r < 2; ++r) {
      const int rg = h * 2 + r;
      gload16(aptr[rg] + k0, &As[b][(rg * 64 + (w << 3)) << 6]);
    }
  };
  auto stageBh = [&](int tl, int h) {
    const int b = tl & 1;
    const int k0 = (tl % NT) << 6;
#pragma unroll
    for (int r = 0; r < 2; ++r) {
      const int rg = h * 2 + r;
      gload16(bptr[rg] + k0, &Bs[b][(rg * 64 + (w << 3)) << 6]);
    }
  };

  f32x4 acc[8][4] = {};
  short8 alo[4], ahi[4];
  const int sw0 = (lq ^ (l15 & 7)) << 3;

  // prologue: tile 0's 4 halves in consumption order (no drain; ph1's vmcnt covers it)
  stageAh(0, 0);
  stageBh(0, 0);
  stageBh(0, 1);
  stageAh(0, 1);

#define VM6_BAR                                                                     \
  asm volatile("s_waitcnt vmcnt(6)" ::: "memory");                                  \
  __builtin_amdgcn_s_barrier();                                                     \
  asm volatile("" ::: "memory");
#define BAR_ONLY                                                                    \
  asm volatile("" ::: "memory");                                                    \
  __builtin_amdgcn_s_barrier();                                                     \
  asm volatile("" ::: "memory");

#define PHASE(BUF, MH, NH)                                                          \
  {                                                                                 \
    if ((NH) == 0) {                                                                \
      _Pragma("unroll")                                                             \
      for (int mm = 0; mm < 4; ++mm) {                                              \
        const unsigned short* ab =                                                  \
            &As[BUF][(((MH) * 128 + wr * 64 + mm * 16 + l15) << 6)];                \
        alo[mm] = *(const short8*)&ab[sw0];                                         \
        ahi[mm] = *(const short8*)&ab[sw0 ^ 32];                                    \
      }                                                                             \
    }                                                                               \
    short8 blo[2], bhi[2];                                                          \
    _Pragma("unroll")                                                               \
    for (int nn = 0; nn < 2; ++nn) {                                                \
      const unsigned short* bb =                                                    \
          &Bs[BUF][(((NH) * 128 + wc * 32 + nn * 16 + l15) << 6)];                  \
      blo[nn] = *(const short8*)&bb[sw0];                                           \
      bhi[nn] = *(const short8*)&bb[sw0 ^ 32];                                      \
    }                                                                               \
    asm volatile("" ::: "memory");                                                  \
    __builtin_amdgcn_s_setprio(1);                                                  \
    _Pragma("unroll")                                                               \
    for (int mm = 0; mm < 4; ++mm)                                                  \
      _Pragma("unroll")                                                             \
      for (int nn = 0; nn < 2; ++nn) {                                              \
        acc[(MH) * 4 + mm][(NH) * 2 + nn] =                                         \
            __builtin_amdgcn_mfma_f32_16x16x32_bf16(                                \
                alo[mm], blo[nn], acc[(MH) * 4 + mm][(NH) * 2 + nn], 0, 0, 0);      \
        acc[(MH) * 4 + mm][(NH) * 2 + nn] =                                         \
            __builtin_amdgcn_mfma_f32_16x16x32_bf16(                                \
                ahi[mm], bhi[nn], acc[(MH) * 4 + mm][(NH) * 2 + nn], 0, 0, 0);      \
      }                                                                             \
    __builtin_amdgcn_s_setprio(0);                                                  \
  }

  for (int t = 0; t < NT; ++t) {
    const int cur = t & 1;
    // ph1 (0,0): stage A0(t+1); need A0(t),B0(t) -> allow {B1(t),A1(t),A0(t+1)} = 6
    stageAh(t + 1, 0);
    VM6_BAR
    PHASE(cur, 0, 0)
    // ph2 (0,1): stage B0(t+1); need B1(t) -> allow {A1(t),A0(t+1),B0(t+1)} = 6
    stageBh(t + 1, 0);
    VM6_BAR
    PHASE(cur, 0, 1)
    // ph3 (1,0): stage B1(t+1); need A1(t) -> allow {A0,B0,B1}(t+1) = 6
    stageBh(t + 1, 1);
    VM6_BAR
    PHASE(cur, 1, 0)
    // ph4 (1,1): stage A1(t+1); nothing new needed (A1 @ph3, B1 @ph2)
    stageAh(t + 1, 1);
    BAR_ONLY
    PHASE(cur, 1, 1)
  }
#undef PHASE
#undef VM6_BAR
#undef BAR_ONLY

  // --- epilogue: h = relu(acc + b1) bf16; striped row/col mapping ---
  const float* be = bias + (size_t)e * NTOT;
#pragma unroll
  for (int m = 0; m < 8; ++m) {
#pragma unroll
    for (int q2 = 0; q2 < 4; ++q2) {
      int row = (m >> 2) * 128 + wr * 64 + (m & 3) * 16 + lq * 4 + q2;
      if (t0 + row < c) {
        unsigned short* hr = hout + (size_t)(base + row) * NTOT;
#pragma unroll
        for (int nn = 0; nn < 4; ++nn) {
          int col = n0 + (nn >> 1) * 128 + wc * 32 + (nn & 1) * 16 + l15;
          float v = acc[m][nn][q2] + be[col];
          v = v > 0.f ? v : 0.f;
          hr[col] = f2bf(v);
        }
      }
    }
  }
}

// ---------------- GEMM2: round-6 proven kernel (BM=128, BK=32, BN=64, split-K) ----------------
template <int KTOT, int NTOT, int BN, bool FIRST, int KSPLIT>
__global__ __launch_bounds__(256) void k_gemm(const unsigned short* __restrict__ Asrc,
                                              const unsigned short* __restrict__ Bsrc,
                                              const float* __restrict__ bias,
                                              const int* __restrict__ cnt,
                                              const int* __restrict__ offs,
                                              const int2* __restrict__ tinfo,
                                              const int* __restrict__ cap,
                                              unsigned short* __restrict__ hout,
                                              float* __restrict__ yout) {
  const int2 ti = tinfo[blockIdx.y];
  if (ti.x < 0) return;
  const int e = ti.x, t0 = ti.y;
  const int c = cnt[e];
  const int base = offs[e] + t0;
  const int n0 = blockIdx.x * BN;
  constexpr int KCH = KTOT / KSPLIT;
  constexpr int NT = KCH / 32;
  const int kb = blockIdx.z * KCH;

  const int tid = threadIdx.x, w = tid >> 6, lane = tid & 63;
  const int l15 = lane & 15, lq = lane >> 4;
  constexpr int MR = 4;
  constexpr int NR = BN / 32;
  constexpr int BR = BN / 64;
  const int wr = w >> 1, wc = w & 1;

  __shared__ unsigned short As[2][128 * 32];
  __shared__ unsigned short Bs[2][BN * 32];

  const int rl = tid >> 2;
  const int sw = (((tid & 3) ^ (rl & 3) ^ ((rl >> 2) & 3)) << 3);
  const unsigned short* aptr[2];
#pragma unroll
  for (int r = 0; r < 2; ++r) {
    int row = r * 64 + rl;
    size_t gr;
    if constexpr (FIRST) gr = (size_t)((t0 + row < c) ? cap[e * NTOKS + t0 + row] : NTOKS);
    else                 gr = (size_t)(base + row);
    aptr[r] = Asrc + gr * (size_t)KTOT + kb + sw;
  }
  const unsigned short* Be = Bsrc + (size_t)e * ((size_t)KTOT * NTOT);
  const unsigned short* bptr[BR];
#pragma unroll
  for (int r = 0; r < BR; ++r)
    bptr[r] = Be + (size_t)(n0 + r * 64 + rl) * KTOT + kb + sw;

  auto stageA = [&](int k0, int b) {
#pragma unroll
    for (int r = 0; r < 2; ++r)
      gload16(aptr[r] + k0, &As[b][(r * 64 + w * 16) << 5]);
  };
  auto stageB = [&](int k0, int b) {
#pragma unroll
    for (int r = 0; r < BR; ++r)
      gload16(bptr[r] + k0, &Bs[b][(r * 64 + w * 16) << 5]);
  };

  f32x4 acc[MR][NR] = {};

  stageA(0, 0);
  stageB(0, 0);
  __syncthreads();

  int buf = 0;
  for (int t = 0; t < NT; ++t) {
    const int nxt = buf ^ 1;
    if (t + 1 < NT) { stageA((t + 1) * 32, nxt); stageB((t + 1) * 32, nxt); }

    short8 a[MR], b[NR];
    const int sw0 = ((lq ^ (l15 & 3) ^ ((l15 >> 2) & 3)) << 3);
#pragma unroll
    for (int m = 0; m < MR; ++m)
      a[m] = *(const short8*)&As[buf][((wr * 64 + m * 16 + l15) << 5) + sw0];
#pragma unroll
    for (int nn = 0; nn < NR; ++nn)
      b[nn] = *(const short8*)&Bs[buf][((wc * (BN / 2) + nn * 16 + l15) << 5) + sw0];
#pragma unroll
    for (int m = 0; m < MR; ++m)
#pragma unroll
      for (int nn = 0; nn < NR; ++nn)
        acc[m][nn] = __builtin_amdgcn_mfma_f32_16x16x32_bf16(a[m], b[nn], acc[m][nn], 0, 0, 0);

    __syncthreads();
    buf = nxt;
  }

  if constexpr (FIRST) {
    const float* be = bias + (size_t)e * NTOT;
#pragma unroll
    for (int m = 0; m < MR; ++m) {
#pragma unroll
      for (int q2 = 0; q2 < 4; ++q2) {
        int row = wr * 64 + m * 16 + lq * 4 + q2;
        if (t0 + row < c) {
          unsigned short* hr = hout + (size_t)(base + row) * NTOT;
#pragma unroll
          for (int nn = 0; nn < NR; ++nn) {
            int col = n0 + wc * (BN / 2) + nn * 16 + l15;
            float v = acc[m][nn][q2] + be[col];
            v = v > 0.f ? v : 0.f;
            hr[col] = f2bf(v);
          }
        }
      }
    }
  } else {
    float* yz = yout + (size_t)blockIdx.z * NTOKS * 2 * DMODEL;
#pragma unroll
    for (int m = 0; m < MR; ++m) {
#pragma unroll
      for (int q2 = 0; q2 < 4; ++q2) {
        int row = wr * 64 + m * 16 + lq * 4 + q2;
        if (t0 + row < c) {
          float* yr = yz + (size_t)(base + row) * NTOT;
#pragma unroll
          for (int nn = 0; nn < NR; ++nn) {
            int col = n0 + wc * (BN / 2) + nn * 16 + l15;
            yr[col] = acc[m][nn][q2];
          }
        }
      }
    }
  }
}

// ---------------- kernel 6: combine (one block per token; sums split-K slabs) ----------------
__global__ __launch_bounds__(256) void k_combine(const float* __restrict__ y,
                                                 const float* __restrict__ b2,
                                                 const int* __restrict__ tok_e,
                                                 const int* __restrict__ tok_t,
                                                 const float* __restrict__ tok_s,
                                                 const int* __restrict__ offs,
                                                 float* __restrict__ out) {
  const int n = blockIdx.x, t = threadIdx.x;
  const float* y1 = y + (size_t)NTOKS * 2 * DMODEL;
  const int e0 = tok_e[2 * n], e1 = tok_e[2 * n + 1];
  const int s0i = offs[e0] + tok_t[2 * n];
  const int s1i = offs[e1] + tok_t[2 * n + 1];
  const float sc0 = tok_s[2 * n], sc1 = tok_s[2 * n + 1];
  f32x4 v0 = *(const f32x4*)(y + (size_t)s0i * DMODEL + t * 4);
  f32x4 u0 = *(const f32x4*)(y1 + (size_t)s0i * DMODEL + t * 4);
  f32x4 v1 = *(const f32x4*)(y + (size_t)s1i * DMODEL + t * 4);
  f32x4 u1 = *(const f32x4*)(y1 + (size_t)s1i * DMODEL + t * 4);
  f32x4 c0 = *(const f32x4*)(b2 + (size_t)e0 * DMODEL + t * 4);
  f32x4 c1 = *(const f32x4*)(b2 + (size_t)e1 * DMODEL + t * 4);
  f32x4 r = sc0 * ((v0 + u0) + c0) + sc1 * ((v1 + u1) + c1);
  *(f32x4*)(out + (size_t)n * DMODEL + t * 4) = r;
}

extern "C" void kernel_launch(void* const* d_in, const int* in_sizes, int n_in,
                              void* d_out, int out_size, void* d_ws, size_t ws_size,
                              hipStream_t stream) {
  const float* x  = (const float*)d_in[0];
  const float* Wg = (const float*)d_in[1];
  const float* bg = (const float*)d_in[2];
  const float* W1 = (const float*)d_in[3];
  const float* b1 = (const float*)d_in[4];
  const float* W2 = (const float*)d_in[5];
  const float* b2 = (const float*)d_in[6];
  float* out = (float*)d_out;

  char* ws = (char*)d_ws;
  unsigned short* xb = (unsigned short*)(ws + OFF_XB);
  int*   cnt   = (int*)(ws + OFF_CNT);
  int*   offs  = (int*)(ws + OFF_OFFS);
  int*   tok_e = (int*)(ws + OFF_TOKE);
  int*   tok_t = (int*)(ws + OFF_TOKT);
  float* tok_s = (float*)(ws + OFF_TOKS);
  int2*  ti256 = (int2*)(ws + OFF_TI);
  int2*  ti128 = (int2*)(ws + OFF_TI2);
  int*   cap   = (int*)(ws + OFF_CAP);
  unsigned short* h  = (unsigned short*)(ws + OFF_H);
  float* y = (float*)(ws + OFF_Y);
  unsigned short* wb = (unsigned short*)(ws + OFF_WB);   // reused: W1T then W2T

  const int convBlocks = (int)(((size_t)(NTOKS + 1) * DMODEL / 8 + 255) / 256);
  k_convert<<<convBlocks, 256, 0, stream>>>(x, xb, cnt);
  k_gate<<<NTOKS / 4, 256, 0, stream>>>(x, Wg, bg, cnt, tok_e, tok_t, tok_s, cap);
  k_scan<<<1, 64, 0, stream>>>(cnt, offs, ti256, ti128);

  // W1 [E][D][DFF] -> wb [E][DFF][D] bf16
  k_transconv<DMODEL, DFFN><<<dim3(DFFN / 64, DMODEL / 64, NEXP), 256, 0, stream>>>(W1, wb);
  // GEMM1: 256^2 counted-vmcnt half-tile pipeline
  k_gemm8<<<dim3(DFFN / 256, TS256), 512, 0, stream>>>(
      xb, wb, b1, cnt, offs, ti256, cap, h);

  // W2 [E][DFF][D] -> wb [E][D][DFF] bf16 (reuse buffer)
  k_transconv<DFFN, DMODEL><<<dim3(DMODEL / 64, DFFN / 64, NEXP), 256, 0, stream>>>(W2, wb);
  // GEMM2: round-6 proven structure, split-K=2
  k_gemm<DFFN, DMODEL, 64, false, 2><<<dim3(DMODEL / 64, TS128, 2), 256, 0, stream>>>(
      h, wb, nullptr, cnt, offs, ti128, cap, nullptr, y);

  k_combine<<<NTOKS, 256, 0, stream>>>(y, b2, tok_e, tok_t, tok_s, offs, out);
}

// Round 11
// 264.723 us; speedup vs baseline: 1.1099x; 1.1099x over previous
//
#include <hip/hip_runtime.h>
#include <hip/hip_bf16.h>
#include <cstdint>
#include <cstddef>

#define NTOKS  2048
#define DMODEL 1024
#define DFFN   4096
#define NEXP   8
#define TS128  40   // max live 128-row M-tiles: sum_e ceil(c_e/128) <= 32+7

typedef __attribute__((ext_vector_type(8))) short short8;
typedef __attribute__((ext_vector_type(4))) float f32x4;
typedef __attribute__((ext_vector_type(4))) unsigned short u16x4;
typedef __attribute__((ext_vector_type(8))) unsigned short u16x8;

// ---------------- workspace layout ----------------
// y (33.5 MB) overlays wbA (67 MB): wbA dead after K3 (gemm1), y written in gemm2.
static constexpr size_t alignup(size_t x) { return (x + 255) & ~(size_t)255; }
static constexpr size_t OFF_XB   = 0;                                            // (NTOKS+1) x DMODEL bf16
static constexpr size_t OFF_CNT  = alignup(OFF_XB + (size_t)(NTOKS + 1) * DMODEL * 2);
static constexpr size_t OFF_OFFS = OFF_CNT + 256;
static constexpr size_t OFF_TOKE = OFF_OFFS + 256;
static constexpr size_t OFF_TOKT = OFF_TOKE + (size_t)NTOKS * 2 * 4;
static constexpr size_t OFF_TOKS = OFF_TOKT + (size_t)NTOKS * 2 * 4;
static constexpr size_t OFF_TI2  = alignup(OFF_TOKS + (size_t)NTOKS * 2 * 4);    // TS128 int2
static constexpr size_t OFF_CAP  = alignup(OFF_TI2 + TS128 * 8);                 // NEXP*NTOKS int
static constexpr size_t OFF_H    = alignup(OFF_CAP + (size_t)NEXP * NTOKS * 4);  // (4096+128) x DFFN bf16
static constexpr size_t OFF_WBA  = alignup(OFF_H + (size_t)(NTOKS * 2 + 128) * DFFN * 2); // E*D*DFF bf16 (W1T)
static constexpr size_t OFF_WBB  = alignup(OFF_WBA + (size_t)NEXP * DMODEL * DFFN * 2);   // E*DFF*D bf16 (W2T)
static constexpr size_t OFF_Y    = OFF_WBA;                                      // alias (2 slabs f32)

__device__ inline unsigned short f2bf(float f) {
  __hip_bfloat16 h = __float2bfloat16(f);
  return __builtin_bit_cast(unsigned short, h);
}

__device__ inline void gload16(const void* g, void* l) {
  __builtin_amdgcn_global_load_lds((const __attribute__((address_space(1))) unsigned int*)g,
                                   (__attribute__((address_space(3))) unsigned int*)l, 16, 0, 0);
}

// ================= role bodies (all 256-thread) =================

// ---- x f32 -> bf16 (+zero row at NTOKS) ----
__device__ __forceinline__ void conv_body(const float* __restrict__ x,
                                          unsigned short* __restrict__ xb, int vb) {
  size_t base = ((size_t)vb * 256 + threadIdx.x) * 8;
  const size_t total = (size_t)(NTOKS + 1) * DMODEL;
  if (base >= total) return;
  u16x8 o;
  if (base < (size_t)NTOKS * DMODEL) {
    f32x4 a = *(const f32x4*)(x + base);
    f32x4 b = *(const f32x4*)(x + base + 4);
#pragma unroll
    for (int j = 0; j < 4; ++j) { o[j] = f2bf(a[j]); o[4 + j] = f2bf(b[j]); }
  } else {
#pragma unroll
    for (int j = 0; j < 8; ++j) o[j] = 0;
  }
  *(u16x8*)(xb + base) = o;
}

// ---- weight transpose+convert: W[e][R][C] f32 -> WT[e][C][R] bf16 ----
template <int R, int C>
__device__ __forceinline__ void tc_body(const float* __restrict__ W,
                                        unsigned short* __restrict__ WT,
                                        int bx, int by, int bz,
                                        unsigned short (*T)[66]) {
  const int e = bz;
  const int c0 = bx * 64, r0 = by * 64;
  const float* Wp = W + (size_t)e * R * C;
  unsigned short* Tp = WT + (size_t)e * R * C;
  const int tid = threadIdx.x;
  const int rr = tid >> 4, cc = (tid & 15) << 2;
#pragma unroll
  for (int i = 0; i < 4; ++i) {
    int r = rr + (i << 4);
    f32x4 v = *(const f32x4*)(Wp + (size_t)(r0 + r) * C + c0 + cc);
    T[r][cc]     = f2bf(v[0]);
    T[r][cc + 1] = f2bf(v[1]);
    T[r][cc + 2] = f2bf(v[2]);
    T[r][cc + 3] = f2bf(v[3]);
  }
  __syncthreads();
  const int c = tid >> 2, kc = (tid & 3) << 4;
  u16x8 o0, o1;
#pragma unroll
  for (int i = 0; i < 8; ++i) { o0[i] = T[kc + i][c]; o1[i] = T[kc + 8 + i][c]; }
  unsigned short* dst = Tp + (size_t)(c0 + c) * R + r0 + kc;
  *(u16x8*)(dst) = o0;
  *(u16x8*)(dst + 8) = o1;
}

// ---- gate: one wave per token (cnt pre-zeroed via hipMemsetAsync) ----
__device__ __forceinline__ void gate_body(const float* __restrict__ x,
                                          const float* __restrict__ Wg,
                                          const float* __restrict__ bg,
                                          int* __restrict__ cnt,
                                          int* __restrict__ tok_e,
                                          int* __restrict__ tok_t,
                                          float* __restrict__ tok_s,
                                          int* __restrict__ cap, int vb) {
  const int w = threadIdx.x >> 6, lane = threadIdx.x & 63;
  const int n = vb * 4 + w;
  float acc[8];
#pragma unroll
  for (int e = 0; e < 8; ++e) acc[e] = 0.f;
  const float* xr = x + (size_t)n * DMODEL;
#pragma unroll 4
  for (int it = 0; it < DMODEL / 64; ++it) {
    int d = it * 64 + lane;
    float xv = xr[d];
    f32x4 w0 = *(const f32x4*)(Wg + d * 8);
    f32x4 w1 = *(const f32x4*)(Wg + d * 8 + 4);
#pragma unroll
    for (int j = 0; j < 4; ++j) { acc[j] += xv * w0[j]; acc[4 + j] += xv * w1[j]; }
  }
#pragma unroll
  for (int e = 0; e < 8; ++e)
#pragma unroll
    for (int off = 32; off; off >>= 1) acc[e] += __shfl_xor(acc[e], off, 64);
  if (lane == 0) {
    float l[8];
#pragma unroll
    for (int e = 0; e < 8; ++e) l[e] = acc[e] + bg[e];
    int i0 = 0; float v0 = l[0];
#pragma unroll
    for (int e = 1; e < 8; ++e) if (l[e] > v0) { v0 = l[e]; i0 = e; }
    int i1 = (i0 == 0) ? 1 : 0; float v1 = l[i1];
#pragma unroll
    for (int e = 0; e < 8; ++e) if (e != i0 && l[e] > v1) { v1 = l[e]; i1 = e; }
    float t = expf(v1 - v0);
    float inv = 1.f / (1.f + t);
    float s0 = inv, s1 = t * inv;
    int t0 = atomicAdd(&cnt[i0], 1);
    int t1 = atomicAdd(&cnt[i1], 1);
    cap[i0 * NTOKS + t0] = n;
    cap[i1 * NTOKS + t1] = n;
    tok_e[2 * n] = i0; tok_e[2 * n + 1] = i1;
    tok_t[2 * n] = t0; tok_t[2 * n + 1] = t1;
    tok_s[2 * n] = s0; tok_s[2 * n + 1] = s1;
  }
}

// ---- grouped GEMM body: round-6 proven (BM=128, BK=32, double-buffered, XOR-swz) ----
template <int KTOT, int NTOT, int BN, bool FIRST, int KSPLIT>
__device__ __forceinline__ void gemm_body(const unsigned short* __restrict__ Asrc,
                                          const unsigned short* __restrict__ Bsrc,
                                          const float* __restrict__ bias,
                                          const int* __restrict__ cnt,
                                          const int* __restrict__ offs,
                                          const int2* __restrict__ tinfo,
                                          const int* __restrict__ cap,
                                          unsigned short* __restrict__ hout,
                                          float* __restrict__ yout,
                                          int bx, int by, int bz, char* smem) {
  const int2 ti = tinfo[by];
  if (ti.x < 0) return;
  const int e = ti.x, t0 = ti.y;
  const int c = cnt[e];
  const int base = offs[e] + t0;
  const int n0 = bx * BN;
  constexpr int KCH = KTOT / KSPLIT;
  constexpr int NT = KCH / 32;
  const int kb = bz * KCH;

  const int tid = threadIdx.x, w = tid >> 6, lane = tid & 63;
  const int l15 = lane & 15, lq = lane >> 4;
  constexpr int MR = 4;
  constexpr int NR = BN / 32;
  constexpr int BR = BN / 64;
  const int wr = w >> 1, wc = w & 1;

  unsigned short (*As)[128 * 32] = (unsigned short (*)[128 * 32])smem;
  unsigned short (*Bs)[BN * 32]  = (unsigned short (*)[BN * 32])(smem + 2 * 128 * 32 * 2);

  const int rl = tid >> 2;
  const int sw = (((tid & 3) ^ (rl & 3) ^ ((rl >> 2) & 3)) << 3);
  const unsigned short* aptr[2];
#pragma unroll
  for (int r = 0; r < 2; ++r) {
    int row = r * 64 + rl;
    size_t gr;
    if constexpr (FIRST) gr = (size_t)((t0 + row < c) ? cap[e * NTOKS + t0 + row] : NTOKS);
    else                 gr = (size_t)(base + row);
    aptr[r] = Asrc + gr * (size_t)KTOT + kb + sw;
  }
  const unsigned short* Be = Bsrc + (size_t)e * ((size_t)KTOT * NTOT);
  const unsigned short* bptr[BR];
#pragma unroll
  for (int r = 0; r < BR; ++r)
    bptr[r] = Be + (size_t)(n0 + r * 64 + rl) * KTOT + kb + sw;

  auto stageA = [&](int k0, int b) {
#pragma unroll
    for (int r = 0; r < 2; ++r)
      gload16(aptr[r] + k0, &As[b][(r * 64 + w * 16) << 5]);
  };
  auto stageB = [&](int k0, int b) {
#pragma unroll
    for (int r = 0; r < BR; ++r)
      gload16(bptr[r] + k0, &Bs[b][(r * 64 + w * 16) << 5]);
  };

  f32x4 acc[MR][NR] = {};

  stageA(0, 0);
  stageB(0, 0);
  __syncthreads();

  int buf = 0;
  for (int t = 0; t < NT; ++t) {
    const int nxt = buf ^ 1;
    if (t + 1 < NT) { stageA((t + 1) * 32, nxt); stageB((t + 1) * 32, nxt); }

    short8 a[MR], b[NR];
    const int sw0 = ((lq ^ (l15 & 3) ^ ((l15 >> 2) & 3)) << 3);
#pragma unroll
    for (int m = 0; m < MR; ++m)
      a[m] = *(const short8*)&As[buf][((wr * 64 + m * 16 + l15) << 5) + sw0];
#pragma unroll
    for (int nn = 0; nn < NR; ++nn)
      b[nn] = *(const short8*)&Bs[buf][((wc * (BN / 2) + nn * 16 + l15) << 5) + sw0];
#pragma unroll
    for (int m = 0; m < MR; ++m)
#pragma unroll
      for (int nn = 0; nn < NR; ++nn)
        acc[m][nn] = __builtin_amdgcn_mfma_f32_16x16x32_bf16(a[m], b[nn], acc[m][nn], 0, 0, 0);

    __syncthreads();
    buf = nxt;
  }

  if constexpr (FIRST) {
    const float* be = bias + (size_t)e * NTOT;
#pragma unroll
    for (int m = 0; m < MR; ++m) {
#pragma unroll
      for (int q2 = 0; q2 < 4; ++q2) {
        int row = wr * 64 + m * 16 + lq * 4 + q2;
        if (t0 + row < c) {
          unsigned short* hr = hout + (size_t)(base + row) * NTOT;
#pragma unroll
          for (int nn = 0; nn < NR; ++nn) {
            int col = n0 + wc * (BN / 2) + nn * 16 + l15;
            float v = acc[m][nn][q2] + be[col];
            v = v > 0.f ? v : 0.f;
            hr[col] = f2bf(v);
          }
        }
      }
    }
  } else {
    float* yz = yout + (size_t)bz * NTOKS * 2 * DMODEL;
#pragma unroll
    for (int m = 0; m < MR; ++m) {
#pragma unroll
      for (int q2 = 0; q2 < 4; ++q2) {
        int row = wr * 64 + m * 16 + lq * 4 + q2;
        if (t0 + row < c) {
          float* yr = yz + (size_t)(base + row) * NTOT;
#pragma unroll
          for (int nn = 0; nn < NR; ++nn) {
            int col = n0 + wc * (BN / 2) + nn * 16 + l15;
            yr[col] = acc[m][nn][q2];
          }
        }
      }
    }
  }
}

// ================= fused phase kernels =================

// K1: [tc1 (W1 -> wbA)  ||  convert (x -> xb)  ||  gate]  -- all independent
__global__ __launch_bounds__(256) void k_phase1(const float* __restrict__ x,
                                                const float* __restrict__ Wg,
                                                const float* __restrict__ bg,
                                                const float* __restrict__ W1,
                                                unsigned short* __restrict__ xb,
                                                unsigned short* __restrict__ wbA,
                                                int* __restrict__ cnt,
                                                int* __restrict__ tok_e,
                                                int* __restrict__ tok_t,
                                                float* __restrict__ tok_s,
                                                int* __restrict__ cap) {
  __shared__ unsigned short T[64][66];
  constexpr int NTC1 = (DFFN / 64) * (DMODEL / 64) * NEXP;   // 8192
  constexpr int NCV  = (int)(((size_t)(NTOKS + 1) * DMODEL / 8 + 255) / 256);  // 1025
  const int b = blockIdx.x;
  if (b < NTC1) {
    const int bx = b & 63, by = (b >> 6) & 15, bz = b >> 10;
    tc_body<DMODEL, DFFN>(W1, wbA, bx, by, bz, T);
  } else if (b < NTC1 + NCV) {
    conv_body(x, xb, b - NTC1);
  } else {
    gate_body(x, Wg, bg, cnt, tok_e, tok_t, tok_s, cap, b - NTC1 - NCV);
  }
}

// K2: offsets + dense live-tile table
__global__ void k_scan(const int* __restrict__ cnt, int* __restrict__ offs,
                       int2* __restrict__ ti128) {
  if (threadIdx.x == 0) {
    int s = 0;
#pragma unroll
    for (int e = 0; e < NEXP; ++e) { offs[e] = s; s += cnt[e]; }
    int b = 0;
    for (int e = 0; e < NEXP; ++e)
      for (int t = 0; t * 128 < cnt[e]; ++t) { ti128[b] = make_int2(e, t * 128); ++b; }
    for (; b < TS128; ++b) ti128[b] = make_int2(-1, 0);
  }
}

// K3: [gemm1 (xb x wbA -> h)  ||  tc2 (W2 -> wbB)] -- independent; gemm1 at low ids
__global__ __launch_bounds__(256) void k_phase3(const unsigned short* __restrict__ xb,
                                                const unsigned short* __restrict__ wbA,
                                                const float* __restrict__ b1,
                                                const float* __restrict__ W2,
                                                unsigned short* __restrict__ wbB,
                                                const int* __restrict__ cnt,
                                                const int* __restrict__ offs,
                                                const int2* __restrict__ ti128,
                                                const int* __restrict__ cap,
                                                unsigned short* __restrict__ h) {
  __shared__ __align__(16) char smem[2 * 128 * 32 * 2 + 2 * 128 * 32 * 2];  // 32 KB
  constexpr int NG1 = (DFFN / 128) * TS128;   // 1280
  const int b = blockIdx.x;
  if (b < NG1) {
    gemm_body<DMODEL, DFFN, 128, true, 1>(xb, wbA, b1, cnt, offs, ti128, cap, h, nullptr,
                                          b & 31, b >> 5, 0, smem);
  } else {
    const int t = b - NG1;
    const int bx = t & 15, by = (t >> 4) & 63, bz = t >> 10;
    tc_body<DFFN, DMODEL>(W2, wbB, bx, by, bz, (unsigned short (*)[66])smem);
  }
}

// K4: gemm2 standalone (round-6 proven; BN=64, split-K=2)
template <int KTOT, int NTOT, int BN, bool FIRST, int KSPLIT>
__global__ __launch_bounds__(256) void k_gemm(const unsigned short* __restrict__ Asrc,
                                              const unsigned short* __restrict__ Bsrc,
                                              const float* __restrict__ bias,
                                              const int* __restrict__ cnt,
                                              const int* __restrict__ offs,
                                              const int2* __restrict__ tinfo,
                                              const int* __restrict__ cap,
                                              unsigned short* __restrict__ hout,
                                              float* __restrict__ yout) {
  __shared__ __align__(16) char smem[2 * 128 * 32 * 2 + 2 * BN * 32 * 2];
  gemm_body<KTOT, NTOT, BN, FIRST, KSPLIT>(Asrc, Bsrc, bias, cnt, offs, tinfo, cap,
                                           hout, yout, blockIdx.x, blockIdx.y, blockIdx.z, smem);
}

// K5: combine (one block per token; sums split-K slabs; fixed order -> deterministic)
__global__ __launch_bounds__(256) void k_combine(const float* __restrict__ y,
                                                 const float* __restrict__ b2,
                                                 const int* __restrict__ tok_e,
                                                 const int* __restrict__ tok_t,
                                                 const float* __restrict__ tok_s,
                                                 const int* __restrict__ offs,
                                                 float* __restrict__ out) {
  const int n = blockIdx.x, t = threadIdx.x;
  const float* y1 = y + (size_t)NTOKS * 2 * DMODEL;
  const int e0 = tok_e[2 * n], e1 = tok_e[2 * n + 1];
  const int s0i = offs[e0] + tok_t[2 * n];
  const int s1i = offs[e1] + tok_t[2 * n + 1];
  const float sc0 = tok_s[2 * n], sc1 = tok_s[2 * n + 1];
  f32x4 v0 = *(const f32x4*)(y + (size_t)s0i * DMODEL + t * 4);
  f32x4 u0 = *(const f32x4*)(y1 + (size_t)s0i * DMODEL + t * 4);
  f32x4 v1 = *(const f32x4*)(y + (size_t)s1i * DMODEL + t * 4);
  f32x4 u1 = *(const f32x4*)(y1 + (size_t)s1i * DMODEL + t * 4);
  f32x4 c0 = *(const f32x4*)(b2 + (size_t)e0 * DMODEL + t * 4);
  f32x4 c1 = *(const f32x4*)(b2 + (size_t)e1 * DMODEL + t * 4);
  f32x4 r = sc0 * ((v0 + u0) + c0) + sc1 * ((v1 + u1) + c1);
  *(f32x4*)(out + (size_t)n * DMODEL + t * 4) = r;
}

extern "C" void kernel_launch(void* const* d_in, const int* in_sizes, int n_in,
                              void* d_out, int out_size, void* d_ws, size_t ws_size,
                              hipStream_t stream) {
  const float* x  = (const float*)d_in[0];
  const float* Wg = (const float*)d_in[1];
  const float* bg = (const float*)d_in[2];
  const float* W1 = (const float*)d_in[3];
  const float* b1 = (const float*)d_in[4];
  const float* W2 = (const float*)d_in[5];
  const float* b2 = (const float*)d_in[6];
  float* out = (float*)d_out;

  char* ws = (char*)d_ws;
  unsigned short* xb = (unsigned short*)(ws + OFF_XB);
  int*   cnt   = (int*)(ws + OFF_CNT);
  int*   offs  = (int*)(ws + OFF_OFFS);
  int*   tok_e = (int*)(ws + OFF_TOKE);
  int*   tok_t = (int*)(ws + OFF_TOKT);
  float* tok_s = (float*)(ws + OFF_TOKS);
  int2*  ti128 = (int2*)(ws + OFF_TI2);
  int*   cap   = (int*)(ws + OFF_CAP);
  unsigned short* h   = (unsigned short*)(ws + OFF_H);
  unsigned short* wbA = (unsigned short*)(ws + OFF_WBA);
  unsigned short* wbB = (unsigned short*)(ws + OFF_WBB);
  float* y = (float*)(ws + OFF_Y);   // overlays wbA (dead by then)

  constexpr int NTC1 = (DFFN / 64) * (DMODEL / 64) * NEXP;   // 8192
  constexpr int NCV  = (int)(((size_t)(NTOKS + 1) * DMODEL / 8 + 255) / 256);  // 1025
  constexpr int NGT  = NTOKS / 4;                            // 512
  constexpr int NG1  = (DFFN / 128) * TS128;                 // 1280
  constexpr int NTC2 = (DMODEL / 64) * (DFFN / 64) * NEXP;   // 8192

  hipMemsetAsync(ws + OFF_CNT, 0, 256, stream);
  k_phase1<<<NTC1 + NCV + NGT, 256, 0, stream>>>(x, Wg, bg, W1, xb, wbA, cnt,
                                                 tok_e, tok_t, tok_s, cap);
  k_scan<<<1, 64, 0, stream>>>(cnt, offs, ti128);
  k_phase3<<<NG1 + NTC2, 256, 0, stream>>>(xb, wbA, b1, W2, wbB, cnt, offs, ti128, cap, h);
  k_gemm<DFFN, DMODEL, 64, false, 2><<<dim3(DMODEL / 64, TS128, 2), 256, 0, stream>>>(
      h, wbB, nullptr, cnt, offs, ti128, cap, nullptr, y);
  k_combine<<<NTOKS, 256, 0, stream>>>(y, b2, tok_e, tok_t, tok_s, offs, out);
}

// Round 12
// 234.630 us; speedup vs baseline: 1.2522x; 1.1283x over previous
//
#include <hip/hip_runtime.h>
#include <hip/hip_bf16.h>
#include <cstdint>
#include <cstddef>

#define NTOKS  2048
#define DMODEL 1024
#define DFFN   4096
#define NEXP   8
#define TS128  40   // max live 128-row M-tiles: sum_e ceil(c_e/128) <= 32+7

typedef __attribute__((ext_vector_type(8))) short short8;
typedef __attribute__((ext_vector_type(4))) float f32x4;
typedef __attribute__((ext_vector_type(4))) unsigned short u16x4;
typedef __attribute__((ext_vector_type(8))) unsigned short u16x8;

// ---------------- workspace layout ----------------
// y (33.5 MB) overlays wbA (67 MB): wbA dead after K3 (gemm1), y written in gemm2.
static constexpr size_t alignup(size_t x) { return (x + 255) & ~(size_t)255; }
static constexpr size_t OFF_XB   = 0;                                            // (NTOKS+1) x DMODEL bf16
static constexpr size_t OFF_CNT  = alignup(OFF_XB + (size_t)(NTOKS + 1) * DMODEL * 2);
static constexpr size_t OFF_OFFS = OFF_CNT + 256;
static constexpr size_t OFF_TOKE = OFF_OFFS + 256;
static constexpr size_t OFF_TOKT = OFF_TOKE + (size_t)NTOKS * 2 * 4;
static constexpr size_t OFF_TOKS = OFF_TOKT + (size_t)NTOKS * 2 * 4;
static constexpr size_t OFF_TI2  = alignup(OFF_TOKS + (size_t)NTOKS * 2 * 4);    // TS128 int2
static constexpr size_t OFF_CAP  = alignup(OFF_TI2 + TS128 * 8);                 // NEXP*NTOKS int
static constexpr size_t OFF_H    = alignup(OFF_CAP + (size_t)NEXP * NTOKS * 4);  // (4096+128) x DFFN bf16
static constexpr size_t OFF_WBA  = alignup(OFF_H + (size_t)(NTOKS * 2 + 128) * DFFN * 2); // E*D*DFF bf16 (W1T)
static constexpr size_t OFF_WBB  = alignup(OFF_WBA + (size_t)NEXP * DMODEL * DFFN * 2);   // E*DFF*D bf16 (W2T)
static constexpr size_t OFF_Y    = OFF_WBA;                                      // alias (2 slabs f32)

__device__ inline unsigned short f2bf(float f) {
  __hip_bfloat16 h = __float2bfloat16(f);
  return __builtin_bit_cast(unsigned short, h);
}

__device__ inline void gload16(const void* g, void* l) {
  __builtin_amdgcn_global_load_lds((const __attribute__((address_space(1))) unsigned int*)g,
                                   (__attribute__((address_space(3))) unsigned int*)l, 16, 0, 0);
}

// ================= role bodies (all 256-thread) =================

// ---- x f32 -> bf16 (+zero row at NTOKS) ----
__device__ __forceinline__ void conv_body(const float* __restrict__ x,
                                          unsigned short* __restrict__ xb, int vb) {
  size_t base = ((size_t)vb * 256 + threadIdx.x) * 8;
  const size_t total = (size_t)(NTOKS + 1) * DMODEL;
  if (base >= total) return;
  u16x8 o;
  if (base < (size_t)NTOKS * DMODEL) {
    f32x4 a = *(const f32x4*)(x + base);
    f32x4 b = *(const f32x4*)(x + base + 4);
#pragma unroll
    for (int j = 0; j < 4; ++j) { o[j] = f2bf(a[j]); o[4 + j] = f2bf(b[j]); }
  } else {
#pragma unroll
    for (int j = 0; j < 8; ++j) o[j] = 0;
  }
  *(u16x8*)(xb + base) = o;
}

// ---- weight transpose+convert: W[e][R][C] f32 -> WT[e][C][R] bf16 ----
template <int R, int C>
__device__ __forceinline__ void tc_body(const float* __restrict__ W,
                                        unsigned short* __restrict__ WT,
                                        int bx, int by, int bz,
                                        unsigned short (*T)[66]) {
  const int e = bz;
  const int c0 = bx * 64, r0 = by * 64;
  const float* Wp = W + (size_t)e * R * C;
  unsigned short* Tp = WT + (size_t)e * R * C;
  const int tid = threadIdx.x;
  const int rr = tid >> 4, cc = (tid & 15) << 2;
#pragma unroll
  for (int i = 0; i < 4; ++i) {
    int r = rr + (i << 4);
    f32x4 v = *(const f32x4*)(Wp + (size_t)(r0 + r) * C + c0 + cc);
    T[r][cc]     = f2bf(v[0]);
    T[r][cc + 1] = f2bf(v[1]);
    T[r][cc + 2] = f2bf(v[2]);
    T[r][cc + 3] = f2bf(v[3]);
  }
  __syncthreads();
  const int c = tid >> 2, kc = (tid & 3) << 4;
  u16x8 o0, o1;
#pragma unroll
  for (int i = 0; i < 8; ++i) { o0[i] = T[kc + i][c]; o1[i] = T[kc + 8 + i][c]; }
  unsigned short* dst = Tp + (size_t)(c0 + c) * R + r0 + kc;
  *(u16x8*)(dst) = o0;
  *(u16x8*)(dst + 8) = o1;
}

// ---- gate: one wave per token; ATOMIC-FREE (writes tok_e/tok_s only) ----
__device__ __forceinline__ void gate_body(const float* __restrict__ x,
                                          const float* __restrict__ Wg,
                                          const float* __restrict__ bg,
                                          int* __restrict__ tok_e,
                                          float* __restrict__ tok_s, int vb) {
  const int w = threadIdx.x >> 6, lane = threadIdx.x & 63;
  const int n = vb * 4 + w;
  float acc[8];
#pragma unroll
  for (int e = 0; e < 8; ++e) acc[e] = 0.f;
  const float* xr = x + (size_t)n * DMODEL;
#pragma unroll 4
  for (int it = 0; it < DMODEL / 64; ++it) {
    int d = it * 64 + lane;
    float xv = xr[d];
    f32x4 w0 = *(const f32x4*)(Wg + d * 8);
    f32x4 w1 = *(const f32x4*)(Wg + d * 8 + 4);
#pragma unroll
    for (int j = 0; j < 4; ++j) { acc[j] += xv * w0[j]; acc[4 + j] += xv * w1[j]; }
  }
#pragma unroll
  for (int e = 0; e < 8; ++e)
#pragma unroll
    for (int off = 32; off; off >>= 1) acc[e] += __shfl_xor(acc[e], off, 64);
  if (lane == 0) {
    float l[8];
#pragma unroll
    for (int e = 0; e < 8; ++e) l[e] = acc[e] + bg[e];
    int i0 = 0; float v0 = l[0];
#pragma unroll
    for (int e = 1; e < 8; ++e) if (l[e] > v0) { v0 = l[e]; i0 = e; }
    int i1 = (i0 == 0) ? 1 : 0; float v1 = l[i1];
#pragma unroll
    for (int e = 0; e < 8; ++e) if (e != i0 && l[e] > v1) { v1 = l[e]; i1 = e; }
    float t = expf(v1 - v0);
    float inv = 1.f / (1.f + t);
    tok_e[2 * n] = i0; tok_e[2 * n + 1] = i1;
    tok_s[2 * n] = inv; tok_s[2 * n + 1] = t * inv;
  }
}

// ---- grouped GEMM body: round-6 proven (BM=128, BK=32, double-buffered, XOR-swz) ----
template <int KTOT, int NTOT, int BN, bool FIRST, int KSPLIT>
__device__ __forceinline__ void gemm_body(const unsigned short* __restrict__ Asrc,
                                          const unsigned short* __restrict__ Bsrc,
                                          const float* __restrict__ bias,
                                          const int* __restrict__ cnt,
                                          const int* __restrict__ offs,
                                          const int2* __restrict__ tinfo,
                                          const int* __restrict__ cap,
                                          unsigned short* __restrict__ hout,
                                          float* __restrict__ yout,
                                          int bx, int by, int bz, char* smem) {
  const int2 ti = tinfo[by];
  if (ti.x < 0) return;
  const int e = ti.x, t0 = ti.y;
  const int c = cnt[e];
  const int base = offs[e] + t0;
  const int n0 = bx * BN;
  constexpr int KCH = KTOT / KSPLIT;
  constexpr int NT = KCH / 32;
  const int kb = bz * KCH;

  const int tid = threadIdx.x, w = tid >> 6, lane = tid & 63;
  const int l15 = lane & 15, lq = lane >> 4;
  constexpr int MR = 4;
  constexpr int NR = BN / 32;
  constexpr int BR = BN / 64;
  const int wr = w >> 1, wc = w & 1;

  unsigned short (*As)[128 * 32] = (unsigned short (*)[128 * 32])smem;
  unsigned short (*Bs)[BN * 32]  = (unsigned short (*)[BN * 32])(smem + 2 * 128 * 32 * 2);

  const int rl = tid >> 2;
  const int sw = (((tid & 3) ^ (rl & 3) ^ ((rl >> 2) & 3)) << 3);
  const unsigned short* aptr[2];
#pragma unroll
  for (int r = 0; r < 2; ++r) {
    int row = r * 64 + rl;
    size_t gr;
    if constexpr (FIRST) gr = (size_t)((t0 + row < c) ? cap[e * NTOKS + t0 + row] : NTOKS);
    else                 gr = (size_t)(base + row);
    aptr[r] = Asrc + gr * (size_t)KTOT + kb + sw;
  }
  const unsigned short* Be = Bsrc + (size_t)e * ((size_t)KTOT * NTOT);
  const unsigned short* bptr[BR];
#pragma unroll
  for (int r = 0; r < BR; ++r)
    bptr[r] = Be + (size_t)(n0 + r * 64 + rl) * KTOT + kb + sw;

  auto stageA = [&](int k0, int b) {
#pragma unroll
    for (int r = 0; r < 2; ++r)
      gload16(aptr[r] + k0, &As[b][(r * 64 + w * 16) << 5]);
  };
  auto stageB = [&](int k0, int b) {
#pragma unroll
    for (int r = 0; r < BR; ++r)
      gload16(bptr[r] + k0, &Bs[b][(r * 64 + w * 16) << 5]);
  };

  f32x4 acc[MR][NR] = {};

  stageA(0, 0);
  stageB(0, 0);
  __syncthreads();

  int buf = 0;
  for (int t = 0; t < NT; ++t) {
    const int nxt = buf ^ 1;
    if (t + 1 < NT) { stageA((t + 1) * 32, nxt); stageB((t + 1) * 32, nxt); }

    short8 a[MR], b[NR];
    const int sw0 = ((lq ^ (l15 & 3) ^ ((l15 >> 2) & 3)) << 3);
#pragma unroll
    for (int m = 0; m < MR; ++m)
      a[m] = *(const short8*)&As[buf][((wr * 64 + m * 16 + l15) << 5) + sw0];
#pragma unroll
    for (int nn = 0; nn < NR; ++nn)
      b[nn] = *(const short8*)&Bs[buf][((wc * (BN / 2) + nn * 16 + l15) << 5) + sw0];
#pragma unroll
    for (int m = 0; m < MR; ++m)
#pragma unroll
      for (int nn = 0; nn < NR; ++nn)
        acc[m][nn] = __builtin_amdgcn_mfma_f32_16x16x32_bf16(a[m], b[nn], acc[m][nn], 0, 0, 0);

    __syncthreads();
    buf = nxt;
  }

  if constexpr (FIRST) {
    const float* be = bias + (size_t)e * NTOT;
#pragma unroll
    for (int m = 0; m < MR; ++m) {
#pragma unroll
      for (int q2 = 0; q2 < 4; ++q2) {
        int row = wr * 64 + m * 16 + lq * 4 + q2;
        if (t0 + row < c) {
          unsigned short* hr = hout + (size_t)(base + row) * NTOT;
#pragma unroll
          for (int nn = 0; nn < NR; ++nn) {
            int col = n0 + wc * (BN / 2) + nn * 16 + l15;
            float v = acc[m][nn][q2] + be[col];
            v = v > 0.f ? v : 0.f;
            hr[col] = f2bf(v);
          }
        }
      }
    }
  } else {
    float* yz = yout + (size_t)bz * NTOKS * 2 * DMODEL;
#pragma unroll
    for (int m = 0; m < MR; ++m) {
#pragma unroll
      for (int q2 = 0; q2 < 4; ++q2) {
        int row = wr * 64 + m * 16 + lq * 4 + q2;
        if (t0 + row < c) {
          float* yr = yz + (size_t)(base + row) * NTOT;
#pragma unroll
          for (int nn = 0; nn < NR; ++nn) {
            int col = n0 + wc * (BN / 2) + nn * 16 + l15;
            yr[col] = acc[m][nn][q2];
          }
        }
      }
    }
  }
}

// ================= fused phase kernels =================

// K1: [tc1 (W1 -> wbA)  ||  convert (x -> xb)  ||  gate (atomic-free)]
__global__ __launch_bounds__(256) void k_phase1(const float* __restrict__ x,
                                                const float* __restrict__ Wg,
                                                const float* __restrict__ bg,
                                                const float* __restrict__ W1,
                                                unsigned short* __restrict__ xb,
                                                unsigned short* __restrict__ wbA,
                                                int* __restrict__ tok_e,
                                                float* __restrict__ tok_s) {
  __shared__ unsigned short T[64][66];
  constexpr int NTC1 = (DFFN / 64) * (DMODEL / 64) * NEXP;   // 8192
  constexpr int NCV  = (int)(((size_t)(NTOKS + 1) * DMODEL / 8 + 255) / 256);  // 1025
  const int b = blockIdx.x;
  if (b < NTC1) {
    const int bx = b & 63, by = (b >> 6) & 15, bz = b >> 10;
    tc_body<DMODEL, DFFN>(W1, wbA, bx, by, bz, T);
  } else if (b < NTC1 + NCV) {
    conv_body(x, xb, b - NTC1);
  } else {
    gate_body(x, Wg, bg, tok_e, tok_s, b - NTC1 - NCV);
  }
}

// K2: deterministic atomic-free routing. 8 waves; wave e ballot-compacts expert e
// over the 4096 (token,k) entries in ascending order -> cap (token-sorted), tok_t,
// cnt; then thread 0 builds offs + live-tile table.
__global__ __launch_bounds__(512) void k_scan(const int* __restrict__ tok_e,
                                              int* __restrict__ cnt,
                                              int* __restrict__ offs,
                                              int* __restrict__ tok_t,
                                              int* __restrict__ cap,
                                              int2* __restrict__ ti128) {
  __shared__ int scnt[NEXP];
  const int w = threadIdx.x >> 6, lane = threadIdx.x & 63;
  if (w < NEXP) {
    const int e = w;
    int t = 0;
    for (int it = 0; it < (NTOKS * 2) / 64; ++it) {
      const int j = it * 64 + lane;
      const bool p = (tok_e[j] == e);
      const unsigned long long m = __ballot(p);
      const int pos = __popcll(m & ((1ull << lane) - 1ull));
      if (p) {
        cap[e * NTOKS + t + pos] = j >> 1;
        tok_t[j] = t + pos;
      }
      t += __popcll(m);
    }
    if (lane == 0) { scnt[e] = t; cnt[e] = t; }
  }
  __syncthreads();
  if (threadIdx.x == 0) {
    int s = 0;
#pragma unroll
    for (int e = 0; e < NEXP; ++e) { offs[e] = s; s += scnt[e]; }
    int b = 0;
    for (int e = 0; e < NEXP; ++e)
      for (int t = 0; t * 128 < scnt[e]; ++t) { ti128[b] = make_int2(e, t * 128); ++b; }
    for (; b < TS128; ++b) ti128[b] = make_int2(-1, 0);
  }
}

// K3: [gemm1 (xb x wbA -> h)  ||  tc2 (W2 -> wbB)] -- independent; gemm1 at low ids
__global__ __launch_bounds__(256) void k_phase3(const unsigned short* __restrict__ xb,
                                                const unsigned short* __restrict__ wbA,
                                                const float* __restrict__ b1,
                                                const float* __restrict__ W2,
                                                unsigned short* __restrict__ wbB,
                                                const int* __restrict__ cnt,
                                                const int* __restrict__ offs,
                                                const int2* __restrict__ ti128,
                                                const int* __restrict__ cap,
                                                unsigned short* __restrict__ h) {
  __shared__ __align__(16) char smem[2 * 128 * 32 * 2 + 2 * 128 * 32 * 2];  // 32 KB
  constexpr int NG1 = (DFFN / 128) * TS128;   // 1280
  const int b = blockIdx.x;
  if (b < NG1) {
    gemm_body<DMODEL, DFFN, 128, true, 1>(xb, wbA, b1, cnt, offs, ti128, cap, h, nullptr,
                                          b & 31, b >> 5, 0, smem);
  } else {
    const int t = b - NG1;
    const int bx = t & 15, by = (t >> 4) & 63, bz = t >> 10;
    tc_body<DFFN, DMODEL>(W2, wbB, bx, by, bz, (unsigned short (*)[66])smem);
  }
}

// K4: gemm2 standalone (round-6 proven; BN=64, split-K=2)
template <int KTOT, int NTOT, int BN, bool FIRST, int KSPLIT>
__global__ __launch_bounds__(256) void k_gemm(const unsigned short* __restrict__ Asrc,
                                              const unsigned short* __restrict__ Bsrc,
                                              const float* __restrict__ bias,
                                              const int* __restrict__ cnt,
                                              const int* __restrict__ offs,
                                              const int2* __restrict__ tinfo,
                                              const int* __restrict__ cap,
                                              unsigned short* __restrict__ hout,
                                              float* __restrict__ yout) {
  __shared__ __align__(16) char smem[2 * 128 * 32 * 2 + 2 * BN * 32 * 2];
  gemm_body<KTOT, NTOT, BN, FIRST, KSPLIT>(Asrc, Bsrc, bias, cnt, offs, tinfo, cap,
                                           hout, yout, blockIdx.x, blockIdx.y, blockIdx.z, smem);
}

// K5: combine (one block per token; sums split-K slabs; fixed order -> deterministic)
__global__ __launch_bounds__(256) void k_combine(const float* __restrict__ y,
                                                 const float* __restrict__ b2,
                                                 const int* __restrict__ tok_e,
                                                 const int* __restrict__ tok_t,
                                                 const float* __restrict__ tok_s,
                                                 const int* __restrict__ offs,
                                                 float* __restrict__ out) {
  const int n = blockIdx.x, t = threadIdx.x;
  const float* y1 = y + (size_t)NTOKS * 2 * DMODEL;
  const int e0 = tok_e[2 * n], e1 = tok_e[2 * n + 1];
  const int s0i = offs[e0] + tok_t[2 * n];
  const int s1i = offs[e1] + tok_t[2 * n + 1];
  const float sc0 = tok_s[2 * n], sc1 = tok_s[2 * n + 1];
  f32x4 v0 = *(const f32x4*)(y + (size_t)s0i * DMODEL + t * 4);
  f32x4 u0 = *(const f32x4*)(y1 + (size_t)s0i * DMODEL + t * 4);
  f32x4 v1 = *(const f32x4*)(y + (size_t)s1i * DMODEL + t * 4);
  f32x4 u1 = *(const f32x4*)(y1 + (size_t)s1i * DMODEL + t * 4);
  f32x4 c0 = *(const f32x4*)(b2 + (size_t)e0 * DMODEL + t * 4);
  f32x4 c1 = *(const f32x4*)(b2 + (size_t)e1 * DMODEL + t * 4);
  f32x4 r = sc0 * ((v0 + u0) + c0) + sc1 * ((v1 + u1) + c1);
  *(f32x4*)(out + (size_t)n * DMODEL + t * 4) = r;
}

extern "C" void kernel_launch(void* const* d_in, const int* in_sizes, int n_in,
                              void* d_out, int out_size, void* d_ws, size_t ws_size,
                              hipStream_t stream) {
  const float* x  = (const float*)d_in[0];
  const float* Wg = (const float*)d_in[1];
  const float* bg = (const float*)d_in[2];
  const float* W1 = (const float*)d_in[3];
  const float* b1 = (const float*)d_in[4];
  const float* W2 = (const float*)d_in[5];
  const float* b2 = (const float*)d_in[6];
  float* out = (float*)d_out;

  char* ws = (char*)d_ws;
  unsigned short* xb = (unsigned short*)(ws + OFF_XB);
  int*   cnt   = (int*)(ws + OFF_CNT);
  int*   offs  = (int*)(ws + OFF_OFFS);
  int*   tok_e = (int*)(ws + OFF_TOKE);
  int*   tok_t = (int*)(ws + OFF_TOKT);
  float* tok_s = (float*)(ws + OFF_TOKS);
  int2*  ti128 = (int2*)(ws + OFF_TI2);
  int*   cap   = (int*)(ws + OFF_CAP);
  unsigned short* h   = (unsigned short*)(ws + OFF_H);
  unsigned short* wbA = (unsigned short*)(ws + OFF_WBA);
  unsigned short* wbB = (unsigned short*)(ws + OFF_WBB);
  float* y = (float*)(ws + OFF_Y);   // overlays wbA (dead by then)

  constexpr int NTC1 = (DFFN / 64) * (DMODEL / 64) * NEXP;   // 8192
  constexpr int NCV  = (int)(((size_t)(NTOKS + 1) * DMODEL / 8 + 255) / 256);  // 1025
  constexpr int NGT  = NTOKS / 4;                            // 512
  constexpr int NG1  = (DFFN / 128) * TS128;                 // 1280
  constexpr int NTC2 = (DMODEL / 64) * (DFFN / 64) * NEXP;   // 8192

  k_phase1<<<NTC1 + NCV + NGT, 256, 0, stream>>>(x, Wg, bg, W1, xb, wbA, tok_e, tok_s);
  k_scan<<<1, 512, 0, stream>>>(tok_e, cnt, offs, tok_t, cap, ti128);
  k_phase3<<<NG1 + NTC2, 256, 0, stream>>>(xb, wbA, b1, W2, wbB, cnt, offs, ti128, cap, h);
  k_gemm<DFFN, DMODEL, 64, false, 2><<<dim3(DMODEL / 64, TS128, 2), 256, 0, stream>>>(
      h, wbB, nullptr, cnt, offs, ti128, cap, nullptr, y);
  k_combine<<<NTOKS, 256, 0, stream>>>(y, b2, tok_e, tok_t, tok_s, offs, out);
}